// Round 3
// baseline (11695.185 us; speedup 1.0000x reference)
//
#include <hip/hip_runtime.h>
#include <hip/hip_bf16.h>
#include <stdint.h>

// ESN sizes (fixed by the reference)
#define NRR     4096
#define NBATCH  16
#define NFEAT   12
#define SEQLEN  1024
#define ALPHA_C 0.6f

typedef _Float16 f16x8 __attribute__((ext_vector_type(8)));
typedef _Float16 f16x2 __attribute__((ext_vector_type(2)));
typedef float    f32x4 __attribute__((ext_vector_type(4)));
typedef unsigned long long u64;

constexpr int WGS    = 128;            // 128 WGs x 32 A-rows each
constexpr int TPB    = 512;            // 8 waves
constexpr int WAVES  = 8;
constexpr int ROWS   = 32;             // A-rows per WG (2 MFMA row-tiles)
constexpr int KCHUNK = NRR / WAVES;    // 512 K per wave
constexpr int FRAGS  = KCHUNK / 32;    // 16 r-fragments per wave per step

#define SC_AGENT __HIP_MEMORY_SCOPE_AGENT

// Relaxed agent-scope ops lower to device-coherent (sc1) memory ops: they
// bypass the non-coherent per-XCD L2s and hit the L3 point of coherence.
// No release/acquire fences anywhere -> no L2 writeback/invalidate storms,
// and read-only inputs stay L2-resident across steps.
__device__ __forceinline__ u64 ldg_u64(const void* p) {
    return __hip_atomic_load((const u64*)p, __ATOMIC_RELAXED, SC_AGENT);
}
__device__ __forceinline__ void stg_u32(void* p, unsigned v) {
    __hip_atomic_store((unsigned*)p, v, __ATOMIC_RELAXED, SC_AGENT);
}
__device__ __forceinline__ void stg_f32(float* p, float v) {
    __hip_atomic_store(p, v, __ATOMIC_RELAXED, SC_AGENT);
}

// Flat grid barrier, fence-free:
//  - per-wave s_waitcnt vmcnt(0): this wave's sc1 stores are committed at L3
//  - __syncthreads: whole WG committed
//  - tid0 relaxed-stores epoch to its own slot
//  - wave0 of EVERY WG polls all 128 slots (64 lanes x one 8B load) -> one
//    L3 round trip from last arrival to release, no master/flag hops
__device__ __forceinline__ void gridbar(unsigned* slots, unsigned epoch,
                                        int wg, int tid, int lane, int wave) {
    asm volatile("s_waitcnt vmcnt(0)" ::: "memory");
    __syncthreads();
    if (tid == 0) stg_u32(&slots[wg], epoch);
    if (wave == 0) {
        const u64* sp = (const u64*)slots;  // 64 lanes x 2 slots = 128
        for (;;) {
            u64 v = ldg_u64(&sp[lane]);
            unsigned a = (unsigned)v, b = (unsigned)(v >> 32);
            if (__all(a >= epoch && b >= epoch)) break;
            __builtin_amdgcn_s_sleep(1);
        }
    }
    __syncthreads();
}

__global__ __launch_bounds__(TPB, 2) void esn_persistent(
    const float* __restrict__ x,    // (16, 1024, 12)
    const float* __restrict__ r0,   // (1, 16, 4096)
    const float* __restrict__ A,    // (4096, 4096) row-major
    const float* __restrict__ Bm,   // (4096, 12)
    const float* __restrict__ bias, // (4096,)
    const float* __restrict__ Cw,   // (8, 4096)
    float* __restrict__ out,        // (16, 8)
    unsigned* __restrict__ slots,   // 128 arrival slots
    _Float16* __restrict__ rb0,     // (16, 4096) fp16 state, double buffer A
    _Float16* __restrict__ rb1,     // buffer B
    float* __restrict__ rfin)       // (16, 4096) fp32 final state
{
    const int wg    = blockIdx.x;
    const int tid   = threadIdx.x;
    const int wave  = tid >> 6;
    const int lane  = tid & 63;
    const int l15   = lane & 15;   // A-frag row-in-tile / B-frag batch col
    const int g     = lane >> 4;   // k-group 0..3
    const int nbase = wg * ROWS;

    __shared__ float lds_red[WAVES][16][ROWS];  // [w][batch][row], XOR-swizzled cols
    __shared__ float lds_x[2][NBATCH][NFEAT];
    __shared__ float lds_Bp[ROWS][NFEAT];
    __shared__ float lds_bias[ROWS];
    __shared__ float lds_out[4][128];

    // ---- A slice -> fp16 register fragments (two 16-row tiles; A read once) ----
    uint4 afrag0[FRAGS], afrag1[FRAGS];
#pragma unroll
    for (int tt = 0; tt < 2; ++tt) {
        const float* arow = A + (size_t)(nbase + tt * 16 + l15) * NRR + wave * KCHUNK + g * 8;
#pragma unroll
        for (int i = 0; i < FRAGS; ++i) {
            const float4* p = (const float4*)(arow + i * 32);
            float4 f0 = p[0];
            float4 f1 = p[1];
            f16x8 h;
            h[0] = (_Float16)f0.x; h[1] = (_Float16)f0.y;
            h[2] = (_Float16)f0.z; h[3] = (_Float16)f0.w;
            h[4] = (_Float16)f1.x; h[5] = (_Float16)f1.y;
            h[6] = (_Float16)f1.z; h[7] = (_Float16)f1.w;
            (tt == 0 ? afrag0 : afrag1)[i] = __builtin_bit_cast(uint4, h);
        }
    }

    // x prefetch mapping (tid<192): thread owns (batch xb, feat xf)
    const int xb = tid / NFEAT;
    const int xf = tid % NFEAT;
    const size_t xofs = (size_t)xb * SEQLEN * NFEAT + xf;

    if (tid < ROWS * NFEAT)
        lds_Bp[tid / NFEAT][tid % NFEAT] = Bm[(size_t)(nbase + tid / NFEAT) * NFEAT + tid % NFEAT];
    if (tid < ROWS)
        lds_bias[tid] = bias[nbase + tid];
    if (tid < NBATCH * NFEAT)
        lds_x[0][xb][xf] = x[xofs];  // x[:, 0, :]

    // ---- master fp32 state: thread owns (batch = tid>>5, row = tid&31) ----
    const int ub = tid >> 5;
    const int un = tid & 31;
    float rm = r0[ub * NRR + nbase + un];
    {
        float hi = __shfl_down(rm, 1);
        if (!(un & 1)) {
            f16x2 h2; h2[0] = (_Float16)rm; h2[1] = (_Float16)hi;
            stg_u32(rb0 + (size_t)ub * NRR + nbase + un,
                    __builtin_bit_cast(unsigned, h2));
        }
    }

    gridbar(slots, 1u, wg, tid, lane, wave);

    const _Float16* rcur = rb0;
    _Float16*       rnxt = rb1;

    const int swz  = (l15 & 7) << 2;       // store-side XOR key (by batch)
    const int rswz = un ^ ((ub & 7) << 2); // read-side swizzled row col

    for (int t = 0; t < SEQLEN; ++t) {
        // kick x[t+1] prefetch (plain cached load; L2 stays warm now)
        float xp = 0.0f;
        if (tid < NBATCH * NFEAT && t + 1 < SEQLEN)
            xp = x[xofs + (size_t)(t + 1) * NFEAT];

        // S[n,b] partials over this wave's K-chunk; r read via sc1 (L3) loads
        f32x4 acc0 = {0.f, 0.f, 0.f, 0.f};
        f32x4 acc1 = {0.f, 0.f, 0.f, 0.f};
        const _Float16* rrow = rcur + l15 * NRR + wave * KCHUNK + g * 8;
#pragma unroll
        for (int i = 0; i < FRAGS; ++i) {
            u64 lo = ldg_u64(rrow + i * 32);
            u64 hi = ldg_u64(rrow + i * 32 + 4);
            uint4 u;
            u.x = (unsigned)lo; u.y = (unsigned)(lo >> 32);
            u.z = (unsigned)hi; u.w = (unsigned)(hi >> 32);
            f16x8 rv = __builtin_bit_cast(f16x8, u);
            acc0 = __builtin_amdgcn_mfma_f32_16x16x32_f16(
                __builtin_bit_cast(f16x8, afrag0[i]), rv, acc0, 0, 0, 0);
            acc1 = __builtin_amdgcn_mfma_f32_16x16x32_f16(
                __builtin_bit_cast(f16x8, afrag1[i]), rv, acc1, 0, 0, 0);
        }
        // D layout: col=lane&15 (batch), row=(lane>>4)*4+j. Store both tiles
        // with XOR-swizzled column -> conflict-free f32x4 ds_writes.
        *(f32x4*)&lds_red[wave][l15][(g * 4) ^ swz]        = acc0;
        *(f32x4*)&lds_red[wave][l15][(16 + g * 4) ^ swz]   = acc1;
        __syncthreads();

        // update: every thread owns one (batch, row) state
        {
            float s = 0.f;
#pragma unroll
            for (int w = 0; w < WAVES; ++w) s += lds_red[w][ub][rswz];
            float p = lds_bias[un];
            const float* xr = lds_x[t & 1][ub];
#pragma unroll
            for (int f = 0; f < NFEAT; ++f) p += lds_Bp[un][f] * xr[f];
            rm = (1.0f - ALPHA_C) * rm + ALPHA_C * tanhf(s + p);
            float hi = __shfl_down(rm, 1);
            if (!(un & 1)) {
                f16x2 h2; h2[0] = (_Float16)rm; h2[1] = (_Float16)hi;
                stg_u32(rnxt + (size_t)ub * NRR + nbase + un,
                        __builtin_bit_cast(unsigned, h2));
            }
            if (t == SEQLEN - 1)
                stg_f32(&rfin[(size_t)ub * NRR + nbase + un], rm);
        }
        // land x prefetch into the other LDS buffer
        if (tid < NBATCH * NFEAT && t + 1 < SEQLEN)
            lds_x[(t + 1) & 1][xb][xf] = xp;

        gridbar(slots, (unsigned)(t + 2), wg, tid, lane, wave);
        _Float16* tmp = (_Float16*)rcur; rcur = rnxt; rnxt = tmp;
    }

    // ---- readout: out[b,o] = sum_k rfin[b,k] * Cw[o,k], by WG 0 ----
    if (wg == 0) {
        const int oi   = tid & 127;  // = b*8 + o
        const int part = tid >> 7;   // K-quarter
        const int b = oi >> 3, o = oi & 7;
        const float* rv = rfin + (size_t)b * NRR + part * (NRR / 4);
        const float* cv = Cw   + (size_t)o * NRR + part * (NRR / 4);
        float s = 0.f;
        for (int k = 0; k < NRR / 4; k += 2) {
            u64 u = ldg_u64(rv + k);
            float ra = __builtin_bit_cast(float, (unsigned)u);
            float rb = __builtin_bit_cast(float, (unsigned)(u >> 32));
            s += ra * cv[k] + rb * cv[k + 1];
        }
        lds_out[part][oi] = s;
        __syncthreads();
        if (tid < 128)
            out[tid] = lds_out[0][tid] + lds_out[1][tid] + lds_out[2][tid] + lds_out[3][tid];
    }
}

extern "C" void kernel_launch(void* const* d_in, const int* in_sizes, int n_in,
                              void* d_out, int out_size, void* d_ws, size_t ws_size,
                              hipStream_t stream) {
    const float* x   = (const float*)d_in[0];
    const float* r0  = (const float*)d_in[1];
    const float* A   = (const float*)d_in[2];
    const float* Bm  = (const float*)d_in[3];
    const float* bv  = (const float*)d_in[4];
    const float* Cw  = (const float*)d_in[5];
    float*       out = (float*)d_out;

    char* ws = (char*)d_ws;
    unsigned*  slots = (unsigned*)ws;                                  // 512 B
    _Float16*  rb0   = (_Float16*)(ws + 2048);                         // 128 KB
    _Float16*  rb1   = (_Float16*)(ws + 2048 + NRR * NBATCH * 2);      // 128 KB
    float*     rfin  = (float*)(ws + 2048 + 2 * (NRR * NBATCH * 2));   // 256 KB

    // slots must start at 0 every call (incl. graph replays)
    hipMemsetAsync(ws, 0, 1024, stream);

    void* args[] = {(void*)&x, (void*)&r0, (void*)&A, (void*)&Bm, (void*)&bv, (void*)&Cw,
                    (void*)&out, (void*)&slots, (void*)&rb0, (void*)&rb1, (void*)&rfin};
    hipError_t e = hipLaunchCooperativeKernel((const void*)esn_persistent,
                                              dim3(WGS), dim3(TPB), args, 0, stream);
    if (e != hipSuccess) {
        hipLaunchKernelGGL(esn_persistent, dim3(WGS), dim3(TPB), 0, stream,
                           x, r0, A, Bm, bv, Cw, out, slots, rb0, rb1, rfin);
    }
}

// Round 4
// 9556.750 us; speedup vs baseline: 1.2238x; 1.2238x over previous
//
#include <hip/hip_runtime.h>
#include <hip/hip_bf16.h>
#include <stdint.h>

// ESN sizes (fixed by the reference)
#define NRR     4096
#define NBATCH  16
#define NFEAT   12
#define SEQLEN  1024
#define ALPHA_C 0.6f

typedef _Float16 f16x8 __attribute__((ext_vector_type(8)));
typedef _Float16 f16x2 __attribute__((ext_vector_type(2)));
typedef float    f32x4 __attribute__((ext_vector_type(4)));
typedef unsigned long long u64;

constexpr int WGS    = 256;            // one WG per CU; 16 A-rows each
constexpr int TPB    = 512;            // 8 waves
constexpr int WAVES  = 8;
constexpr int KCHUNK = NRR / WAVES;    // 512 K per wave
constexpr int FRAGS  = KCHUNK / 32;    // 16 MFMAs per wave per step
constexpr int NFLAG  = 16;             // replicated release-flag lines

#define SC_AGENT __HIP_MEMORY_SCOPE_AGENT

// Relaxed agent-scope ops lower to device-coherent (sc1) loads/stores that
// meet at the L3 point of coherence. No release/acquire fences anywhere ->
// no L2 writeback/invalidate storms; read-only inputs stay L2-resident.
// Ordering is provided solely by the per-wave vmcnt(0) drain that
// __syncthreads performs before s_barrier.
__device__ __forceinline__ unsigned ld_rlx(const unsigned* p) {
    return __hip_atomic_load(p, __ATOMIC_RELAXED, SC_AGENT);
}
__device__ __forceinline__ u64 ld_rlx64(const void* p) {
    return __hip_atomic_load((const u64*)p, __ATOMIC_RELAXED, SC_AGENT);
}
__device__ __forceinline__ void st_rlx(unsigned* p, unsigned v) {
    __hip_atomic_store(p, v, __ATOMIC_RELAXED, SC_AGENT);
}
__device__ __forceinline__ void st_rlx_f32(float* p, float v) {
    __hip_atomic_store(p, v, __ATOMIC_RELAXED, SC_AGENT);
}

// Two-level fence-free grid barrier:
//  - __syncthreads: all waves' sc1 stores of this WG are committed (vmcnt drain)
//  - tid0 relaxed-stores epoch into its own arrival slot (no RMW anywhere)
//  - master (WG0 wave0) polls the 256 hot slots alone (64 lanes x 2 u64),
//    then writes 16 replicated flag lines (written ONCE per step)
//  - every other wave self-polls its flag line and proceeds directly:
//    no trailing s_barrier on the critical path. Safe because all intra-WG
//    LDS hazards are separated by the pre-arrival __syncthreads.
__device__ __forceinline__ void gridbar(unsigned* slots, unsigned* flags,
                                        unsigned epoch, int wg, int tid,
                                        int lane, int wave) {
    __syncthreads();
    if (tid == 0) st_rlx(&slots[wg], epoch);
    if ((wg | wave) == 0) {
        const u64* sp = (const u64*)slots;
        const int i0 = lane * 2;
        for (;;) {
            u64 a = ld_rlx64(&sp[i0]);
            u64 b = ld_rlx64(&sp[i0 + 1]);
            bool ok = ((unsigned)a >= epoch) & ((unsigned)(a >> 32) >= epoch) &
                      ((unsigned)b >= epoch) & ((unsigned)(b >> 32) >= epoch);
            if (__all(ok)) break;
            __builtin_amdgcn_s_sleep(1);
        }
        if (lane < NFLAG) st_rlx(&flags[lane * 32], epoch);
    } else {
        const unsigned* f = &flags[(wg & (NFLAG - 1)) * 32];
        while (ld_rlx(f) < epoch) __builtin_amdgcn_s_sleep(1);
    }
}

__global__ __launch_bounds__(TPB, 1) void esn_persistent(
    const float* __restrict__ x,    // (16, 1024, 12)
    const float* __restrict__ r0,   // (1, 16, 4096)
    const float* __restrict__ A,    // (4096, 4096) row-major
    const float* __restrict__ Bm,   // (4096, 12)
    const float* __restrict__ bias, // (4096,)
    const float* __restrict__ Cw,   // (8, 4096)
    float* __restrict__ out,        // (16, 8)
    unsigned* __restrict__ slots,   // 256 arrival slots
    unsigned* __restrict__ flags,   // 16 release flags, 128B apart
    _Float16* __restrict__ rb0,     // (16, 4096) fp16 state, double buffer A
    _Float16* __restrict__ rb1,     // buffer B
    float* __restrict__ rfin)       // (16, 4096) fp32 final state
{
    const int wg    = blockIdx.x;
    const int tid   = threadIdx.x;
    const int wave  = tid >> 6;
    const int lane  = tid & 63;
    const int l15   = lane & 15;   // A-frag row-in-tile / B-frag batch col
    const int g     = lane >> 4;   // k-group 0..3
    const int nbase = wg * 16;

    __shared__ float lds_red[WAVES][16][16];  // [w][batch][row]
    __shared__ float lds_x[2][NBATCH][NFEAT];
    __shared__ float lds_Bp[16][NFEAT];
    __shared__ float lds_bias[16];
    __shared__ float lds_out[4][128];

    // ---- A slice -> fp16 register fragments (A read exactly once) ----
    uint4 afrag[FRAGS];
    {
        const float* arow = A + (size_t)(nbase + l15) * NRR + wave * KCHUNK + g * 8;
#pragma unroll
        for (int i = 0; i < FRAGS; ++i) {
            const float4* p = (const float4*)(arow + i * 32);
            float4 f0 = p[0];
            float4 f1 = p[1];
            f16x8 h;
            h[0] = (_Float16)f0.x; h[1] = (_Float16)f0.y;
            h[2] = (_Float16)f0.z; h[3] = (_Float16)f0.w;
            h[4] = (_Float16)f1.x; h[5] = (_Float16)f1.y;
            h[6] = (_Float16)f1.z; h[7] = (_Float16)f1.w;
            afrag[i] = __builtin_bit_cast(uint4, h);
        }
    }

    // x prefetch mapping (tid<192): thread owns (batch xb, feat xf)
    const int xb = tid / NFEAT;
    const int xf = tid % NFEAT;
    const size_t xofs = (size_t)xb * SEQLEN * NFEAT + xf;

    if (tid < 16 * NFEAT)
        lds_Bp[xb][xf] = Bm[(size_t)(nbase + xb) * NFEAT + xf];
    if (tid < 16)
        lds_bias[tid] = bias[nbase + tid];
    if (tid < NBATCH * NFEAT)
        lds_x[0][xb][xf] = x[xofs];  // x[:, 0, :]

    // ---- master fp32 state: update thread tid<256 owns (batch=tid>>4, n=tid&15) ----
    const int ub = tid >> 4;
    const int un = tid & 15;
    float rm = 0.0f;
    if (tid < 256) {
        rm = r0[ub * NRR + nbase + un];
        float hi = __shfl_down(rm, 1);
        if (!(un & 1)) {
            f16x2 h2; h2[0] = (_Float16)rm; h2[1] = (_Float16)hi;
            st_rlx((unsigned*)(rb0 + (size_t)ub * NRR + nbase + un),
                   __builtin_bit_cast(unsigned, h2));
        }
    }

    gridbar(slots, flags, 1u, wg, tid, lane, wave);

    const _Float16* rcur = rb0;
    _Float16*       rnxt = rb1;

    for (int t = 0; t < SEQLEN; ++t) {
        // kick x[t+1] prefetch (plain cached load; L2 stays warm — no INV)
        float xp = 0.0f;
        if (tid < NBATCH * NFEAT && t + 1 < SEQLEN)
            xp = x[xofs + (size_t)(t + 1) * NFEAT];

        // S[n,b] partials over this wave's K-chunk; r via sc1 (L3-coherent) loads
        f32x4 acc = {0.f, 0.f, 0.f, 0.f};
        const _Float16* rrow = rcur + l15 * NRR + wave * KCHUNK + g * 8;
#pragma unroll
        for (int i = 0; i < FRAGS; ++i) {
            u64 lo = ld_rlx64(rrow + i * 32);
            u64 hi = ld_rlx64(rrow + i * 32 + 4);
            uint4 u;
            u.x = (unsigned)lo; u.y = (unsigned)(lo >> 32);
            u.z = (unsigned)hi; u.w = (unsigned)(hi >> 32);
            acc = __builtin_amdgcn_mfma_f32_16x16x32_f16(
                __builtin_bit_cast(f16x8, afrag[i]),
                __builtin_bit_cast(f16x8, u), acc, 0, 0, 0);
        }
        // D layout: col=lane&15 (batch), row=(lane>>4)*4+j. Store transposed
        // [w][batch][row] as one contiguous f32x4: conflict-free write,
        // 2-way (free) read below.
        *(f32x4*)&lds_red[wave][l15][g * 4] = acc;
        __syncthreads();

        if (tid < 256) {
            float s = 0.f;
#pragma unroll
            for (int w = 0; w < WAVES; ++w) s += lds_red[w][ub][un];
            float p = lds_bias[un];
            const float* xr = lds_x[t & 1][ub];
#pragma unroll
            for (int f = 0; f < NFEAT; ++f) p += lds_Bp[un][f] * xr[f];
            rm = (1.0f - ALPHA_C) * rm + ALPHA_C * tanhf(s + p);
            float hi = __shfl_down(rm, 1);
            if (!(un & 1)) {
                f16x2 h2; h2[0] = (_Float16)rm; h2[1] = (_Float16)hi;
                st_rlx((unsigned*)(rnxt + (size_t)ub * NRR + nbase + un),
                       __builtin_bit_cast(unsigned, h2));
            }
            if (t == SEQLEN - 1)
                st_rlx_f32(&rfin[(size_t)ub * NRR + nbase + un], rm);
        }
        // land x prefetch into the other LDS buffer
        if (tid < NBATCH * NFEAT && t + 1 < SEQLEN)
            lds_x[(t + 1) & 1][xb][xf] = xp;

        gridbar(slots, flags, (unsigned)(t + 2), wg, tid, lane, wave);
        _Float16* tmp = (_Float16*)rcur; rcur = rnxt; rnxt = tmp;
    }

    // ---- readout: out[b,o] = sum_k rfin[b,k] * Cw[o,k], by WG 0 ----
    if (wg == 0) {
        const int oi   = tid & 127;  // = b*8 + o
        const int part = tid >> 7;   // K-quarter
        const int b = oi >> 3, o = oi & 7;
        const float* rv = rfin + (size_t)b * NRR + part * (NRR / 4);
        const float* cv = Cw   + (size_t)o * NRR + part * (NRR / 4);
        float s = 0.f;
        for (int k = 0; k < NRR / 4; k += 2) {
            u64 u = ld_rlx64(rv + k);
            float ra = __builtin_bit_cast(float, (unsigned)u);
            float rb = __builtin_bit_cast(float, (unsigned)(u >> 32));
            s += ra * cv[k] + rb * cv[k + 1];
        }
        lds_out[part][oi] = s;
        __syncthreads();
        if (tid < 128)
            out[tid] = lds_out[0][tid] + lds_out[1][tid] + lds_out[2][tid] + lds_out[3][tid];
    }
}

extern "C" void kernel_launch(void* const* d_in, const int* in_sizes, int n_in,
                              void* d_out, int out_size, void* d_ws, size_t ws_size,
                              hipStream_t stream) {
    const float* x   = (const float*)d_in[0];
    const float* r0  = (const float*)d_in[1];
    const float* A   = (const float*)d_in[2];
    const float* Bm  = (const float*)d_in[3];
    const float* bv  = (const float*)d_in[4];
    const float* Cw  = (const float*)d_in[5];
    float*       out = (float*)d_out;

    char* ws = (char*)d_ws;
    unsigned*  slots = (unsigned*)ws;                                  // 1 KB (256 x u32)
    unsigned*  flags = (unsigned*)(ws + 1024);                         // 2 KB (16 lines)
    _Float16*  rb0   = (_Float16*)(ws + 4096);                         // 128 KB
    _Float16*  rb1   = (_Float16*)(ws + 4096 + NRR * NBATCH * 2);      // 128 KB
    float*     rfin  = (float*)(ws + 4096 + 2 * (NRR * NBATCH * 2));   // 256 KB

    // slots/flags must start at 0 every call (incl. graph replays)
    hipMemsetAsync(ws, 0, 4096, stream);

    void* args[] = {(void*)&x, (void*)&r0, (void*)&A, (void*)&Bm, (void*)&bv, (void*)&Cw,
                    (void*)&out, (void*)&slots, (void*)&flags, (void*)&rb0, (void*)&rb1,
                    (void*)&rfin};
    hipError_t e = hipLaunchCooperativeKernel((const void*)esn_persistent,
                                              dim3(WGS), dim3(TPB), args, 0, stream);
    if (e != hipSuccess) {
        hipLaunchKernelGGL(esn_persistent, dim3(WGS), dim3(TPB), 0, stream,
                           x, r0, A, Bm, bv, Cw, out, slots, flags, rb0, rb1, rfin);
    }
}